// Round 7
// baseline (355.832 us; speedup 1.0000x reference)
//
#include <hip/hip_runtime.h>
#include <hip/hip_bf16.h>

// Model_81956565942963: TCN + low-rank dynamic graph + linear head.
// B=16, L=512, N=64, D=128, S=32 x 16, r=8, P=96. f32 in/out.
// R19 (post-mortem R18: reg-dbuf barrier-free GEMM = 160 VGPR of buffers ->
// occupancy/spill regression; tail is memory-parallelism-bound ~165-205us
// across all structures at 1-2 blocks/CU):
//  - g_out v4: R17's proven As-LDS-dbuf BK=128 core, B prefetch one HALF
//    period ahead (48 VGPR not 96); split-K x2 (adj is G-independent, mix is
//    linear in G -> each kh half mixes partial G and atomicAdds out); LDS
//    union {As dbuf} u {Gs+adjn} + e2 in registers -> 47KB -> 3 blocks/CU.
//    1024 blocks, 8 barrier periods each, bid%8==s%8 XCD locality kept.

#define BATCH 16
#define SEQ 512
#define NVAR 64
#define DM 128
#define SEG 32
#define SCL 16
#define RNK 8
#define PRED 96
#define BN (BATCH * NVAR)   // 1024
#define ROWLEN (SEQ * DM)   // 65536

typedef unsigned short ushort_t;
typedef __attribute__((ext_vector_type(8))) short short8;   // 8 bf16
typedef __attribute__((ext_vector_type(4))) float f32x4;

__device__ inline float bf2f(ushort_t u) {
    union { unsigned int i; float f; } x;
    x.i = ((unsigned int)u) << 16;
    return x.f;
}
__device__ inline ushort_t f2bf(float f) {
    union { float f; unsigned int i; } u;
    u.f = f;
    unsigned int x = u.i;
    return (ushort_t)((x + 0x7fffu + ((x >> 16) & 1u)) >> 16);  // RNE
}
__device__ inline unsigned int pkbf(float a, float b) {  // packed bf16 pair
    __hip_bfloat162 h = __float22bfloat162_rn(make_float2(a, b));
    union { __hip_bfloat162 h2; unsigned int u; } c;
    c.h2 = h;
    return c.u;
}
__device__ inline float blo(unsigned int u) {
    union { unsigned int i; float f; } x;
    x.i = u << 16;
    return x.f;
}
__device__ inline float bhi(unsigned int u) {
    union { unsigned int i; float f; } x;
    x.i = u & 0xFFFF0000u;
    return x.f;
}
// gelu(x) = x * sigmoid(2t), t = 0.79788456*x*(1+0.044715*x^2).
// exp(-2t) = 2^(x*(C0 + C1*x^2)), C0 = -2*log2(e)*0.79788456, C1 = C0*0.044715.
__device__ inline float gelu_fast(float x) {
    float x2 = x * x;
    float t2 = x * fmaf(-0.10294854f, x2, -2.3022584f);
    float e;
    asm("v_exp_f32 %0, %1" : "=v"(e) : "v"(t2));
    return x * __builtin_amdgcn_rcpf(1.0f + e);
}

// ---------------- prep: conv weights + FULL head_w transpose + out init -----
// blocks 0..511:     wt part (bx = bid>>7, ci = bid&127; 128 threads used)
// blocks 512..2559:  hw part, k32 tile = bid-512 (0..2047), kbase = tile*32
// blocks 2560..2943: out init: out[b][p][n] = head_b[p]
__global__ __launch_bounds__(256) void prep(
    const float* __restrict__ conv_w, const float* __restrict__ w_emb,
    const float* __restrict__ b_emb, const float* __restrict__ conv_b,
    const float* __restrict__ head_w, const float* __restrict__ head_b,
    ushort_t* __restrict__ WTf, float* __restrict__ Acoef,
    float* __restrict__ Bias3, ushort_t* __restrict__ HWf,
    float* __restrict__ out, float* __restrict__ regacc) {
    __shared__ float ts[32 * 97];
    int bid = blockIdx.x;
    if (bid == 0 && threadIdx.x == 0) regacc[0] = 0.f;
    if (bid < 512) {
        int bx = bid >> 7, ci = bid & 127;
        if (threadIdx.x < 128) {
            int co = threadIdx.x;
            if (bx < 3) {
                // layer-2 tap bx -> frag-major bf16
                int kt = ci >> 5, quad = (ci >> 3) & 3, j = ci & 7;
                int ng = co >> 4, col = co & 15;
                int lane = quad * 16 + col;
                WTf[((((size_t)bx * 4 + kt) * 8 + ng) * 64 + lane) * 8 + j] =
                    f2bf(conv_w[(size_t)(3 + bx) * 16384 + (size_t)ci * 128 + co]);
            } else if (ci == 0) {
                // rank-1 collapse of layer 1
                float a0 = 0.f, a1 = 0.f, a2 = 0.f, c0 = 0.f, c1 = 0.f, c2 = 0.f;
                for (int k = 0; k < 128; ++k) {
                    float we = w_emb[k], be = b_emb[k];
                    float w0 = conv_w[((size_t)(0 * 128 + k)) * 128 + co];
                    float w1 = conv_w[((size_t)(1 * 128 + k)) * 128 + co];
                    float w2 = conv_w[((size_t)(2 * 128 + k)) * 128 + co];
                    a0 += we * w0; c0 += be * w0;
                    a1 += we * w1; c1 += be * w1;
                    a2 += we * w2; c2 += be * w2;
                }
                Acoef[0 * 128 + co] = a0;
                Acoef[1 * 128 + co] = a1;
                Acoef[2 * 128 + co] = a2;
                float b0 = conv_b[co];
                Bias3[0 * 128 + co] = b0 + c2;             // l==0
                Bias3[1 * 128 + co] = b0 + c1 + c2;        // l==1
                Bias3[2 * 128 + co] = b0 + c0 + c1 + c2;   // l>=2
            }
        }
    } else if (bid < 2560) {
        // head_w f32 [k][p] -> bf16 frag-major; tile covers k = tile*32..+31
        int k32p = bid - 512;                 // 0..2047 (= s*64 + kt*2 + kk)
        const float* src = head_w + (size_t)k32p * 32 * 96;
        for (int idx = threadIdx.x; idx < 3072; idx += 256) {
            int kk = idx / 96, p = idx - kk * 96;
            ts[kk * 97 + p] = src[idx];       // fully contiguous read
        }
        __syncthreads();
        unsigned int* ob32 =
            reinterpret_cast<unsigned int*>(HWf + (size_t)k32p * 3072);
        for (int odx = threadIdx.x; odx < 1536; odx += 256) {
            int p = odx >> 4, kk = (odx & 15) * 2;
            ob32[odx] = pkbf(ts[kk * 97 + p], ts[(kk + 1) * 97 + p]);
        }
    } else {
        int idx = (bid - 2560) * 256 + threadIdx.x;
        if (idx < BATCH * PRED * NVAR) {
            int p = (idx >> 6) % PRED;
            out[idx] = head_b[p];
        }
    }
}

// ---------------- fused TCN (layer1 scalar + layer2 MFMA) + z + e1/e2 ------
__global__ __launch_bounds__(256, 4) void tcn_mfma(
    const float* __restrict__ x, const float* __restrict__ w_emb,
    const float* __restrict__ b_emb, const float* __restrict__ Acoef,
    const float* __restrict__ Bias3, const ushort_t* __restrict__ WTf,
    const float* __restrict__ conv_b,
    const float* __restrict__ gw1, const float* __restrict__ gb1,
    const float* __restrict__ gw2, const float* __restrict__ gb2,
    ushort_t* __restrict__ h2, float* __restrict__ e1, float* __restrict__ e2) {
    __shared__ __align__(16) ushort_t h1s[68 * 136];  // h1, row = li+4; later
                                                      // rows 0..63 = staged h2
    __shared__ float xs[70];                          // x[l0-6 .. l0+63]
    __shared__ float zbuf[4 * 136];                   // segment means (pad 136)

    int bn = blockIdx.x;
    int b = bn >> 6, n = bn & 63;
    int chunk = blockIdx.y;
    int l0 = chunk * 64;
    int tid = threadIdx.x;

    // ---- stage x halo (broadcast scalars) ----
    {
        const float* xb = x + (size_t)b * SEQ * NVAR + n;
        if (tid < 70) {
            int l = l0 - 6 + tid;
            xs[tid] = (l >= 0) ? xb[(size_t)l * NVAR] : 0.0f;
        }
    }
    __syncthreads();

    // ---- layer 1 direct: h1[row][d] = gelu(sum_k x*A) + (x*we+be) ----
    {
        int dp = (tid & 63) * 2;
        float2 A0 = *reinterpret_cast<const float2*>(&Acoef[0 * 128 + dp]);
        float2 A1 = *reinterpret_cast<const float2*>(&Acoef[1 * 128 + dp]);
        float2 A2 = *reinterpret_cast<const float2*>(&Acoef[2 * 128 + dp]);
        float2 BF = *reinterpret_cast<const float2*>(&Bias3[2 * 128 + dp]);
        float2 we2 = *reinterpret_cast<const float2*>(&w_emb[dp]);
        float2 be2 = *reinterpret_cast<const float2*>(&b_emb[dp]);
#pragma unroll
        for (int i = 0; i < 17; ++i) {  // 68 rows x 64 pairs = 17*256
            int row = (tid >> 6) + 4 * i;   // wave-uniform
            int l = l0 - 4 + row;
            unsigned int pk = 0;
            if (l >= 0) {
                float x0 = xs[row], x1 = xs[row + 1], x2 = xs[row + 2];
                float2 bias = BF;
                if (l < 2)  // chunk 0, rows 4/5 only (wave-uniform)
                    bias = *reinterpret_cast<const float2*>(&Bias3[l * 128 + dp]);
                float y0 = fmaf(x0, A0.x, fmaf(x1, A1.x, fmaf(x2, A2.x, bias.x)));
                float y1 = fmaf(x0, A0.y, fmaf(x1, A1.y, fmaf(x2, A2.y, bias.y)));
                float r0 = gelu_fast(y0) + fmaf(x2, we2.x, be2.x);
                float r1 = gelu_fast(y1) + fmaf(x2, we2.y, be2.y);
                pk = pkbf(r0, r1);
            }
            *reinterpret_cast<unsigned int*>(&h1s[row * 136 + dp]) = pk;
        }
    }
    __syncthreads();

    int lane = tid & 63;
    int wv = tid >> 6;
    int quad = lane >> 4;
    int col = lane & 15;
    int cobase = wv * 32;

    // ---- layer 2 MFMA: li = mt*16+col; tap t reads h1s row li+2t ----
    f32x4 acc2[4][2];
#pragma unroll
    for (int mt = 0; mt < 4; ++mt)
#pragma unroll
        for (int nt = 0; nt < 2; ++nt)
            acc2[mt][nt] = (f32x4){0.f, 0.f, 0.f, 0.f};

#pragma unroll
    for (int tap = 0; tap < 3; ++tap) {
        short8 wf0[4], wf1[4];
#pragma unroll
        for (int kt = 0; kt < 4; ++kt) {
            const ushort_t* bp =
                WTf + ((((size_t)tap * 4 + kt) * 8 + wv * 2) * 64 + lane) * 8;
            wf0[kt] = *(const short8*)bp;
            wf1[kt] = *(const short8*)(bp + 512);
        }
#pragma unroll
        for (int kt = 0; kt < 4; ++kt) {
            int kc = kt * 32 + quad * 8;
#pragma unroll
            for (int mt = 0; mt < 4; ++mt) {
                short8 hf = *(const short8*)&h1s[(mt * 16 + col + 2 * tap) * 136 + kc];
                acc2[mt][0] = __builtin_amdgcn_mfma_f32_16x16x32_bf16(wf0[kt], hf, acc2[mt][0], 0, 0, 0);
                acc2[mt][1] = __builtin_amdgcn_mfma_f32_16x16x32_bf16(wf1[kt], hf, acc2[mt][1], 0, 0, 0);
            }
        }
    }

    // ---- epilogue 2: residuals -> regs, barrier, then stage h2 into h1s ----
    {
        uint2 res[4][2];
#pragma unroll
        for (int mt = 0; mt < 4; ++mt) {
            int li = mt * 16 + col;
#pragma unroll
            for (int nt = 0; nt < 2; ++nt) {
                int co = cobase + nt * 16 + quad * 4;
                res[mt][nt] = *reinterpret_cast<const uint2*>(
                    &h1s[(li + 4) * 136 + co]);
            }
        }
        __syncthreads();  // all h1 reads done; h1s rows 0..63 become h2 stage
        float4 bias[2];
        bias[0] = *reinterpret_cast<const float4*>(&conv_b[DM + cobase + quad * 4]);
        bias[1] = *reinterpret_cast<const float4*>(&conv_b[DM + cobase + 16 + quad * 4]);
#pragma unroll
        for (int mt = 0; mt < 4; ++mt) {
            int li = mt * 16 + col;
#pragma unroll
            for (int nt = 0; nt < 2; ++nt) {
                int co = cobase + nt * 16 + quad * 4;
                float h0 = gelu_fast(acc2[mt][nt][0] + bias[nt].x) + blo(res[mt][nt].x);
                float h1 = gelu_fast(acc2[mt][nt][1] + bias[nt].y) + bhi(res[mt][nt].x);
                float h2v = gelu_fast(acc2[mt][nt][2] + bias[nt].z) + blo(res[mt][nt].y);
                float h3 = gelu_fast(acc2[mt][nt][3] + bias[nt].w) + bhi(res[mt][nt].y);
                uint2 pk;
                pk.x = pkbf(h0, h1);
                pk.y = pkbf(h2v, h3);
                *reinterpret_cast<uint2*>(&h1s[li * 136 + co]) = pk;
            }
        }
    }
    __syncthreads();

    // ---- coalesced h2 store (from h1s rows 0..63) ----
    {
        ushort_t* orow = h2 + (size_t)bn * ROWLEN + (size_t)l0 * 128;
#pragma unroll
        for (int i = 0; i < 4; ++i) {
            int q = tid + 256 * i;
            int row = q >> 4, c8 = (q & 15) * 8;
            *(short8*)&orow[row * 128 + c8] = *(const short8*)&h1s[row * 136 + c8];
        }
    }
    // ---- z: 4 segment means; thread = (sl, d-pair), b32 reads ----
    {
        int sl = tid >> 6;
        int dp = (tid & 63) * 2;
        float a0 = 0.0f, a1 = 0.0f;
#pragma unroll
        for (int c = 0; c < SCL; ++c) {
            unsigned int u = *reinterpret_cast<const unsigned int*>(
                &h1s[(sl * 16 + c) * 136 + dp]);
            a0 += blo(u);
            a1 += bhi(u);
        }
        zbuf[sl * 136 + dp] = a0 * 0.0625f;
        zbuf[sl * 136 + dp + 1] = a1 * 0.0625f;
    }
    __syncthreads();
    // ---- e1/e2: 64 outputs x 4-way part-interleaved d + shfl reduce ----
    {
        int outi = tid >> 2;         // (sl, which, r)
        int part = tid & 3;          // d residue mod 4
        int sl = outi >> 4;
        int which = (outi >> 3) & 1;
        int r = outi & 7;
        const float* w = which ? gw2 : gw1;
        float a = 0.0f;
#pragma unroll 8
        for (int i = 0; i < 32; ++i) {
            int d = i * 4 + part;    // bank-conflict-free: 16 addrs, 16 banks
            a += zbuf[sl * 136 + d] * w[d * RNK + r];
        }
        a += __shfl_xor(a, 1, 64);
        a += __shfl_xor(a, 2, 64);
        if (part == 0) {
            a += (which ? gb2 : gb1)[r];
            int s = chunk * 4 + sl;
            (which ? e2 : e1)[(((size_t)b * SEG + s) * NVAR + n) * RNK + r] = a;
        }
    }
}

// ---------------- g_out v4: split-K fused GEMM + softmax + mix + reg --------
// grid 1024: bid = kh*512 + b*32 + s (bid%8 == s%8 -> XCD locality for HWf).
// Each block GEMMs its K-half (8 periods of BK=128, As LDS dbuf, B frags
// prefetched one half-period ahead), computes adj[s] from e1/e2 (e2 in regs),
// mixes its partial G, atomicAdds into out. kh==0 also accumulates reg.
__global__ __launch_bounds__(256) void g_out(
    const ushort_t* __restrict__ h2, const ushort_t* __restrict__ HWf,
    const float* __restrict__ e1, const float* __restrict__ e2,
    float* __restrict__ out, float* __restrict__ regacc) {
    // union: {As dbuf 2x64x136 ushort = 34816 B} u {Gs 96x66 + adjn 64x66 f32
    // = 42240 B}. As dead after the k-loop's final barrier.
    __shared__ __align__(16) char smem[42240];
    __shared__ float e1s[2][64][9];   // pad 9: conflict-free
    __shared__ float wsum[4];
    ushort_t* As0 = reinterpret_cast<ushort_t*>(smem);
    ushort_t* As1 = As0 + 64 * 136;
    float* Gs = reinterpret_cast<float*>(smem);            // [96][66]
    float* adjn = reinterpret_cast<float*>(smem + 25344);  // [64][66]

    int bid = blockIdx.x;
    int s = bid & 31, b = (bid >> 5) & 15, kh = bid >> 9;
    int tid = threadIdx.x;
    int lane = tid & 63, wv = tid >> 6;
    int quad = lane >> 4, col = lane & 15;
    int mh = wv & 1;   // m half (32)
    int ph = wv >> 1;  // p half (48)
    int p0 = ph * 48 + col;

    // ---- e2 rows (lane's own m) into registers; e1 slices into LDS ----
    float e2r[2][8];
#pragma unroll
    for (int j = 0; j < 2; ++j) {
        int ss = s - 1 + j;
        if (ss >= 0) {
            const float* p =
                &e2[(((size_t)b * SEG + ss) * NVAR + lane) * RNK];
            float4 v0 = *reinterpret_cast<const float4*>(p);
            float4 v1 = *reinterpret_cast<const float4*>(p + 4);
            e2r[j][0] = v0.x; e2r[j][1] = v0.y; e2r[j][2] = v0.z; e2r[j][3] = v0.w;
            e2r[j][4] = v1.x; e2r[j][5] = v1.y; e2r[j][6] = v1.z; e2r[j][7] = v1.w;
        } else {
#pragma unroll
            for (int r = 0; r < 8; ++r) e2r[j][r] = 0.0f;
        }
    }
    for (int idx = tid; idx < 1024; idx += 256) {
        int j = idx >> 9, nl = (idx >> 3) & 63, r = idx & 7;
        int ss = s - 1 + j;
        e1s[j][nl][r] = (ss >= 0)
            ? e1[(((size_t)b * SEG + ss) * NVAR + nl) * RNK + r] : 0.0f;
    }

    // ---- GEMM over K-half: 8 periods of BK=128 ----
    int arow = tid >> 2;             // 0..63
    int akq = (tid & 3) * 32;        // ushort offset within BK=128 row
    const ushort_t* aptr = h2 +
        (size_t)(b * 64 + arow) * ROWLEN + (size_t)s * 2048 + kh * 1024 + akq;
    // B frag(hp=t*2+tk, kk, i) at hb + hp*6144 + kk*3072 + i*512
    const ushort_t* hb = HWf +
        (size_t)s * 196608 + (size_t)kh * 98304 + (size_t)p0 * 32 + quad * 8;

    f32x4 acc[3][2];  // [p-tile][m-tile]
#pragma unroll
    for (int i = 0; i < 3; ++i)
#pragma unroll
        for (int j = 0; j < 2; ++j) acc[i][j] = (f32x4){0.f, 0.f, 0.f, 0.f};

    short8 pa[4];
    short8 pf[2][2][3];  // [half-period parity][kk][i]
#pragma unroll
    for (int j = 0; j < 4; ++j) pa[j] = *(const short8*)(aptr + j * 8);
#pragma unroll
    for (int kk = 0; kk < 2; ++kk)
#pragma unroll
        for (int i = 0; i < 3; ++i)
            pf[0][kk][i] = *(const short8*)(hb + kk * 3072 + i * 512);
#pragma unroll
    for (int j = 0; j < 4; ++j)
        *(short8*)&As0[arow * 136 + akq + j * 8] = pa[j];
    __syncthreads();

#pragma unroll
    for (int t = 0; t < 8; ++t) {
        const int par = t & 1;
        if (t < 7) {
            const ushort_t* ap = aptr + (t + 1) * 128;
#pragma unroll
            for (int j = 0; j < 4; ++j) pa[j] = *(const short8*)(ap + j * 8);
        }
#pragma unroll
        for (int tk = 0; tk < 2; ++tk) {
            const int hp = t * 2 + tk;
            const int pp = hp & 1;
            if (hp < 15) {
                const ushort_t* fb = hb + (size_t)(hp + 1) * 6144;
#pragma unroll
                for (int kk = 0; kk < 2; ++kk)
#pragma unroll
                    for (int i = 0; i < 3; ++i)
                        pf[pp ^ 1][kk][i] =
                            *(const short8*)(fb + kk * 3072 + i * 512);
            }
            const ushort_t* asb = par ? As1 : As0;
#pragma unroll
            for (int kk = 0; kk < 2; ++kk) {
                int kc = tk * 64 + kk * 32 + quad * 8;
#pragma unroll
                for (int j = 0; j < 2; ++j) {
                    short8 bnfr = *(const short8*)&asb[
                        (mh * 32 + j * 16 + col) * 136 + kc];
#pragma unroll
                    for (int i = 0; i < 3; ++i)
                        acc[i][j] = __builtin_amdgcn_mfma_f32_16x16x32_bf16(
                            pf[pp][kk][i], bnfr, acc[i][j], 0, 0, 0);
                }
            }
        }
        if (t < 7) {
            ushort_t* asn = par ? As0 : As1;
#pragma unroll
            for (int j = 0; j < 4; ++j)
                *(short8*)&asn[arow * 136 + akq + j * 8] = pa[j];
        }
        __syncthreads();
    }

    // ---- stage partial-G slice to LDS (As dead): Gs[p][m] ----
#pragma unroll
    for (int i = 0; i < 3; ++i)
#pragma unroll
        for (int j = 0; j < 2; ++j)
#pragma unroll
            for (int r = 0; r < 4; ++r)
                Gs[(ph * 48 + i * 16 + quad * 4 + r) * 66 +
                   mh * 32 + j * 16 + col] = acc[i][j][r];

    // ---- adj softmax: wave wv does rows wv*16..+15; lane = m ----
    float regsum = 0.0f;
    for (int t = 0; t < 16; ++t) {
        int nl = wv * 16 + t;
        float scC = 0.0f;
#pragma unroll
        for (int r = 0; r < 8; ++r) scC += e1s[1][nl][r] * e2r[1][r];
        scC *= 0.35355339059327373f;  // 1/sqrt(8)
        float mxC = scC;
        for (int off = 32; off; off >>= 1)
            mxC = fmaxf(mxC, __shfl_xor(mxC, off, 64));
        float exC = __expf(scC - mxC);
        float smC = exC;
        for (int off = 32; off; off >>= 1) smC += __shfl_xor(smC, off, 64);
        float aC = exC * __builtin_amdgcn_rcpf(smC);
        adjn[nl * 66 + lane] = aC;
        if (kh == 0 && s > 0) {     // regularizer via prev-s softmax
            float scP = 0.0f;
#pragma unroll
            for (int r = 0; r < 8; ++r) scP += e1s[0][nl][r] * e2r[0][r];
            scP *= 0.35355339059327373f;
            float mxP = scP;
            for (int off = 32; off; off >>= 1)
                mxP = fmaxf(mxP, __shfl_xor(mxP, off, 64));
            float exP = __expf(scP - mxP);
            float smP = exP;
            for (int off = 32; off; off >>= 1) smP += __shfl_xor(smP, off, 64);
            regsum += fabsf(aC - exP * __builtin_amdgcn_rcpf(smP));
        }
    }
    __syncthreads();

    // ---- mix: out[b,p,n] += sum_m adjn[n][m] * Gs[p][m] ----
    {
        int pg = tid >> 4;   // p = pg*6 + j
        int ng = tid & 15;   // n = ng*4 + i
        float ao[6][4];
#pragma unroll
        for (int j = 0; j < 6; ++j)
#pragma unroll
            for (int i = 0; i < 4; ++i) ao[j][i] = 0.f;
#pragma unroll 4
        for (int m = 0; m < 64; m += 2) {
            float2 av[4];
#pragma unroll
            for (int i = 0; i < 4; ++i)
                av[i] = *reinterpret_cast<const float2*>(
                    &adjn[(ng * 4 + i) * 66 + m]);
#pragma unroll
            for (int j = 0; j < 6; ++j) {
                float2 g = *reinterpret_cast<const float2*>(
                    &Gs[(pg * 6 + j) * 66 + m]);
#pragma unroll
                for (int i = 0; i < 4; ++i)
                    ao[j][i] = fmaf(g.x, av[i].x, fmaf(g.y, av[i].y, ao[j][i]));
            }
        }
#pragma unroll
        for (int j = 0; j < 6; ++j)
#pragma unroll
            for (int i = 0; i < 4; ++i)
                atomicAdd(&out[((size_t)b * PRED + pg * 6 + j) * NVAR +
                               ng * 4 + i],
                          ao[j][i]);
    }
    // ---- block-reduce regsum -> one atomic (kh==0 only) ----
    for (int off = 32; off; off >>= 1) regsum += __shfl_xor(regsum, off, 64);
    if (lane == 0) wsum[wv] = regsum;
    __syncthreads();
    if (tid == 0 && kh == 0)
        atomicAdd(regacc, wsum[0] + wsum[1] + wsum[2] + wsum[3]);
}

// ---------------- fin: write regularizer scalar -----------------------------
__global__ void fin(const float* __restrict__ regacc, float* __restrict__ out,
                    int out_size) {
    out[out_size - 1] = regacc[0] * (1.0f / 65536.0f);
}

extern "C" void kernel_launch(void* const* d_in, const int* in_sizes, int n_in,
                              void* d_out, int out_size, void* d_ws,
                              size_t ws_size, hipStream_t stream) {
    const float* x_enc  = (const float*)d_in[0];
    const float* w_emb  = (const float*)d_in[4];
    const float* b_emb  = (const float*)d_in[5];
    const float* conv_w = (const float*)d_in[6];
    const float* conv_b = (const float*)d_in[7];
    const float* gg_w1  = (const float*)d_in[8];
    const float* gg_b1  = (const float*)d_in[9];
    const float* gg_w2  = (const float*)d_in[10];
    const float* gg_b2  = (const float*)d_in[11];
    const float* head_w = (const float*)d_in[12];
    const float* head_b = (const float*)d_in[13];
    float* out = (float*)d_out;

    // workspace (157,286,404 B)
    char* ws = (char*)d_ws;
    ushort_t* h2   = (ushort_t*)(ws);                   // 134,217,728
    float* e1      = (float*)(ws + 134217728);          //   1,048,576
    float* e2      = (float*)(ws + 135266304);          //   1,048,576
    ushort_t* WTf  = (ushort_t*)(ws + 136314880);       //      98,304
    float* Acoef   = (float*)(ws + 136413184);          //       1,536
    float* Bias3   = (float*)(ws + 136414720);          //       1,536
    ushort_t* HWf  = (ushort_t*)(ws + 136416256);       //  12,582,912 (full)
    float* regacc  = (float*)(ws + 157286400);          //           4

    prep<<<2944, 256, 0, stream>>>(
        conv_w, w_emb, b_emb, conv_b, head_w, head_b,
        WTf, Acoef, Bias3, HWf, out, regacc);
    tcn_mfma<<<dim3(BN, SEQ / 64), 256, 0, stream>>>(
        x_enc, w_emb, b_emb, Acoef, Bias3, WTf, conv_b,
        gg_w1, gg_b1, gg_w2, gg_b2, h2, e1, e2);
    g_out<<<1024, 256, 0, stream>>>(h2, HWf, e1, e2, out, regacc);
    fin<<<1, 1, 0, stream>>>(regacc, out, out_size);
}

// Round 9
// 316.261 us; speedup vs baseline: 1.1251x; 1.1251x over previous
//
#include <hip/hip_runtime.h>
#include <hip/hip_bf16.h>

// Model_81956565942963: TCN + low-rank dynamic graph + linear head.
// B=16, L=512, N=64, D=128, S=32 x 16, r=8, P=96. f32 in/out.
// R21 = R20 resubmitted (R20 bench died on container infra, not the kernel).
// R20: full revert to R15 (measured best, 290.4us) + one surgical change:
//  - g_gemm bn-split x2: grid (32 s, 32 bn-slabs of 32 rows). As LDS 18.4->9.2
//    KB, acc 24->12 VGPR, ~4 blocks/CU (was 2), half the per-block chain.
//    Single barrier per k-tile via parity dbuf (proven in R18/R19).
//  Rationale: every fused-tail variant (R16-R19: 308/304/328/356) lost to
//  R15's un-fused tail; its g_gemm already has XCD locality (same-s blocks
//  equal mod 8) and the G round-trip costs only ~8us of BW.

#define BATCH 16
#define SEQ 512
#define NVAR 64
#define DM 128
#define SEG 32
#define SCL 16
#define RNK 8
#define PRED 96
#define BN (BATCH * NVAR)   // 1024
#define ROWLEN (SEQ * DM)   // 65536

typedef unsigned short ushort_t;
typedef __attribute__((ext_vector_type(8))) short short8;   // 8 bf16
typedef __attribute__((ext_vector_type(4))) float f32x4;

__device__ inline float bf2f(ushort_t u) {
    union { unsigned int i; float f; } x;
    x.i = ((unsigned int)u) << 16;
    return x.f;
}
__device__ inline ushort_t f2bf(float f) {
    union { float f; unsigned int i; } u;
    u.f = f;
    unsigned int x = u.i;
    return (ushort_t)((x + 0x7fffu + ((x >> 16) & 1u)) >> 16);  // RNE
}
__device__ inline unsigned int pkbf(float a, float b) {  // packed bf16 pair
    __hip_bfloat162 h = __float22bfloat162_rn(make_float2(a, b));
    union { __hip_bfloat162 h2; unsigned int u; } c;
    c.h2 = h;
    return c.u;
}
__device__ inline float blo(unsigned int u) {
    union { unsigned int i; float f; } x;
    x.i = u << 16;
    return x.f;
}
__device__ inline float bhi(unsigned int u) {
    union { unsigned int i; float f; } x;
    x.i = u & 0xFFFF0000u;
    return x.f;
}
// gelu(x) = x * sigmoid(2t), t = 0.79788456*x*(1+0.044715*x^2).
// exp(-2t) = 2^(x*(C0 + C1*x^2)), C0 = -2*log2(e)*0.79788456, C1 = C0*0.044715.
__device__ inline float gelu_fast(float x) {
    float x2 = x * x;
    float t2 = x * fmaf(-0.10294854f, x2, -2.3022584f);
    float e;
    asm("v_exp_f32 %0, %1" : "=v"(e) : "v"(t2));
    return x * __builtin_amdgcn_rcpf(1.0f + e);
}

// ---------------- prep: conv-weight prep + head_w half 0 + out init ---------
// blocks 0..511:    wt part (bx = bid>>7, ci = bid&127; 128 threads used)
// blocks 512..1535: hw part kh=0 (k32p = bid-512)
// blocks 1536..1919: out init: out[b][p][n] = head_b[p]
__global__ __launch_bounds__(256) void prep(
    const float* __restrict__ conv_w, const float* __restrict__ w_emb,
    const float* __restrict__ b_emb, const float* __restrict__ conv_b,
    const float* __restrict__ head_w, const float* __restrict__ head_b,
    ushort_t* __restrict__ WTf, float* __restrict__ Acoef,
    float* __restrict__ Bias3, ushort_t* __restrict__ HWf,
    float* __restrict__ out, float* __restrict__ regacc) {
    __shared__ float ts[32 * 97];
    int bid = blockIdx.x;
    if (bid == 0 && threadIdx.x == 0) regacc[0] = 0.f;
    if (bid < 512) {
        int bx = bid >> 7, ci = bid & 127;
        if (threadIdx.x < 128) {
            int co = threadIdx.x;
            if (bx < 3) {
                // layer-2 tap bx -> frag-major bf16
                int kt = ci >> 5, quad = (ci >> 3) & 3, j = ci & 7;
                int ng = co >> 4, col = co & 15;
                int lane = quad * 16 + col;
                WTf[((((size_t)bx * 4 + kt) * 8 + ng) * 64 + lane) * 8 + j] =
                    f2bf(conv_w[(size_t)(3 + bx) * 16384 + (size_t)ci * 128 + co]);
            } else if (ci == 0) {
                // rank-1 collapse of layer 1
                float a0 = 0.f, a1 = 0.f, a2 = 0.f, c0 = 0.f, c1 = 0.f, c2 = 0.f;
                for (int k = 0; k < 128; ++k) {
                    float we = w_emb[k], be = b_emb[k];
                    float w0 = conv_w[((size_t)(0 * 128 + k)) * 128 + co];
                    float w1 = conv_w[((size_t)(1 * 128 + k)) * 128 + co];
                    float w2 = conv_w[((size_t)(2 * 128 + k)) * 128 + co];
                    a0 += we * w0; c0 += be * w0;
                    a1 += we * w1; c1 += be * w1;
                    a2 += we * w2; c2 += be * w2;
                }
                Acoef[0 * 128 + co] = a0;
                Acoef[1 * 128 + co] = a1;
                Acoef[2 * 128 + co] = a2;
                float b0 = conv_b[co];
                Bias3[0 * 128 + co] = b0 + c2;
                Bias3[1 * 128 + co] = b0 + c1 + c2;
                Bias3[2 * 128 + co] = b0 + c0 + c1 + c2;
            }
        }
    } else if (bid < 1536) {
        // head_w f32 [k][p] -> bf16 frag-major, kh = 0
        int k32p = bid - 512;                 // 0..1023
        int s = k32p >> 5, t = k32p & 31;
        int kbase = (s * 64 + t) * 32;        // kh=0
        const float* src = head_w + (size_t)kbase * 96;
        for (int idx = threadIdx.x; idx < 3072; idx += 256) {
            int kk = idx / 96, p = idx - kk * 96;
            ts[kk * 97 + p] = src[idx];
        }
        __syncthreads();
        unsigned int* ob32 =
            reinterpret_cast<unsigned int*>(HWf + (size_t)k32p * 3072);
        for (int odx = threadIdx.x; odx < 1536; odx += 256) {
            int p = odx >> 4, kk = (odx & 15) * 2;
            ob32[odx] = pkbf(ts[kk * 97 + p], ts[(kk + 1) * 97 + p]);
        }
    } else {
        int idx = (bid - 1536) * 256 + threadIdx.x;
        if (idx < BATCH * PRED * NVAR) {
            int p = (idx >> 6) % PRED;
            out[idx] = head_b[p];
        }
    }
}

// ---------------- head_w half-transpose (kh=1 between the two g_gemms) ------
__global__ __launch_bounds__(256) void hw_prep(
    const float* __restrict__ head_w, ushort_t* __restrict__ HWf, int kh) {
    __shared__ float ts[32 * 97];
    int k32p = blockIdx.x;                    // 0..1023
    int s = k32p >> 5, t = k32p & 31;
    int kbase = (s * 64 + kh * 32 + t) * 32;
    const float* src = head_w + (size_t)kbase * 96;
    for (int idx = threadIdx.x; idx < 3072; idx += 256) {
        int kk = idx / 96, p = idx - kk * 96;
        ts[kk * 97 + p] = src[idx];
    }
    __syncthreads();
    unsigned int* ob32 =
        reinterpret_cast<unsigned int*>(HWf + (size_t)k32p * 3072);
    for (int odx = threadIdx.x; odx < 1536; odx += 256) {
        int p = odx >> 4, kk = (odx & 15) * 2;
        ob32[odx] = pkbf(ts[kk * 97 + p], ts[(kk + 1) * 97 + p]);
    }
}

// ---------------- fused TCN (layer1 scalar + layer2 MFMA) + z + e1/e2 ------
__global__ __launch_bounds__(256, 4) void tcn_mfma(
    const float* __restrict__ x, const float* __restrict__ w_emb,
    const float* __restrict__ b_emb, const float* __restrict__ Acoef,
    const float* __restrict__ Bias3, const ushort_t* __restrict__ WTf,
    const float* __restrict__ conv_b,
    const float* __restrict__ gw1, const float* __restrict__ gb1,
    const float* __restrict__ gw2, const float* __restrict__ gb2,
    ushort_t* __restrict__ h2, float* __restrict__ e1, float* __restrict__ e2) {
    __shared__ __align__(16) ushort_t h1s[68 * 136];  // h1, row = li+4; later
                                                      // rows 0..63 = staged h2
    __shared__ float xs[70];                          // x[l0-6 .. l0+63]
    __shared__ float zbuf[4 * 136];                   // segment means (pad 136)

    int bn = blockIdx.x;
    int b = bn >> 6, n = bn & 63;
    int chunk = blockIdx.y;
    int l0 = chunk * 64;
    int tid = threadIdx.x;

    // ---- stage x halo (broadcast scalars) ----
    {
        const float* xb = x + (size_t)b * SEQ * NVAR + n;
        if (tid < 70) {
            int l = l0 - 6 + tid;
            xs[tid] = (l >= 0) ? xb[(size_t)l * NVAR] : 0.0f;
        }
    }
    __syncthreads();

    // ---- layer 1 direct: h1[row][d] = gelu(sum_k x*A) + (x*we+be) ----
    {
        int dp = (tid & 63) * 2;
        float2 A0 = *reinterpret_cast<const float2*>(&Acoef[0 * 128 + dp]);
        float2 A1 = *reinterpret_cast<const float2*>(&Acoef[1 * 128 + dp]);
        float2 A2 = *reinterpret_cast<const float2*>(&Acoef[2 * 128 + dp]);
        float2 BF = *reinterpret_cast<const float2*>(&Bias3[2 * 128 + dp]);
        float2 we2 = *reinterpret_cast<const float2*>(&w_emb[dp]);
        float2 be2 = *reinterpret_cast<const float2*>(&b_emb[dp]);
#pragma unroll
        for (int i = 0; i < 17; ++i) {  // 68 rows x 64 pairs = 17*256
            int row = (tid >> 6) + 4 * i;   // wave-uniform
            int l = l0 - 4 + row;
            unsigned int pk = 0;
            if (l >= 0) {
                float x0 = xs[row], x1 = xs[row + 1], x2 = xs[row + 2];
                float2 bias = BF;
                if (l < 2)  // chunk 0, rows 4/5 only (wave-uniform)
                    bias = *reinterpret_cast<const float2*>(&Bias3[l * 128 + dp]);
                float y0 = fmaf(x0, A0.x, fmaf(x1, A1.x, fmaf(x2, A2.x, bias.x)));
                float y1 = fmaf(x0, A0.y, fmaf(x1, A1.y, fmaf(x2, A2.y, bias.y)));
                float r0 = gelu_fast(y0) + fmaf(x2, we2.x, be2.x);
                float r1 = gelu_fast(y1) + fmaf(x2, we2.y, be2.y);
                pk = pkbf(r0, r1);
            }
            *reinterpret_cast<unsigned int*>(&h1s[row * 136 + dp]) = pk;
        }
    }
    __syncthreads();

    int lane = tid & 63;
    int wv = tid >> 6;
    int quad = lane >> 4;
    int col = lane & 15;
    int cobase = wv * 32;

    // ---- layer 2 MFMA: li = mt*16+col; tap t reads h1s row li+2t ----
    f32x4 acc2[4][2];
#pragma unroll
    for (int mt = 0; mt < 4; ++mt)
#pragma unroll
        for (int nt = 0; nt < 2; ++nt)
            acc2[mt][nt] = (f32x4){0.f, 0.f, 0.f, 0.f};

#pragma unroll
    for (int tap = 0; tap < 3; ++tap) {
        short8 wf0[4], wf1[4];
#pragma unroll
        for (int kt = 0; kt < 4; ++kt) {
            const ushort_t* bp =
                WTf + ((((size_t)tap * 4 + kt) * 8 + wv * 2) * 64 + lane) * 8;
            wf0[kt] = *(const short8*)bp;
            wf1[kt] = *(const short8*)(bp + 512);
        }
#pragma unroll
        for (int kt = 0; kt < 4; ++kt) {
            int kc = kt * 32 + quad * 8;
#pragma unroll
            for (int mt = 0; mt < 4; ++mt) {
                short8 hf = *(const short8*)&h1s[(mt * 16 + col + 2 * tap) * 136 + kc];
                acc2[mt][0] = __builtin_amdgcn_mfma_f32_16x16x32_bf16(wf0[kt], hf, acc2[mt][0], 0, 0, 0);
                acc2[mt][1] = __builtin_amdgcn_mfma_f32_16x16x32_bf16(wf1[kt], hf, acc2[mt][1], 0, 0, 0);
            }
        }
    }

    // ---- epilogue 2: residuals -> regs, barrier, then stage h2 into h1s ----
    {
        uint2 res[4][2];
#pragma unroll
        for (int mt = 0; mt < 4; ++mt) {
            int li = mt * 16 + col;
#pragma unroll
            for (int nt = 0; nt < 2; ++nt) {
                int co = cobase + nt * 16 + quad * 4;
                res[mt][nt] = *reinterpret_cast<const uint2*>(
                    &h1s[(li + 4) * 136 + co]);
            }
        }
        __syncthreads();  // all h1 reads done; h1s rows 0..63 become h2 stage
        float4 bias[2];
        bias[0] = *reinterpret_cast<const float4*>(&conv_b[DM + cobase + quad * 4]);
        bias[1] = *reinterpret_cast<const float4*>(&conv_b[DM + cobase + 16 + quad * 4]);
#pragma unroll
        for (int mt = 0; mt < 4; ++mt) {
            int li = mt * 16 + col;
#pragma unroll
            for (int nt = 0; nt < 2; ++nt) {
                int co = cobase + nt * 16 + quad * 4;
                float h0 = gelu_fast(acc2[mt][nt][0] + bias[nt].x) + blo(res[mt][nt].x);
                float h1 = gelu_fast(acc2[mt][nt][1] + bias[nt].y) + bhi(res[mt][nt].x);
                float h2v = gelu_fast(acc2[mt][nt][2] + bias[nt].z) + blo(res[mt][nt].y);
                float h3 = gelu_fast(acc2[mt][nt][3] + bias[nt].w) + bhi(res[mt][nt].y);
                uint2 pk;
                pk.x = pkbf(h0, h1);
                pk.y = pkbf(h2v, h3);
                *reinterpret_cast<uint2*>(&h1s[li * 136 + co]) = pk;
            }
        }
    }
    __syncthreads();

    // ---- coalesced h2 store (from h1s rows 0..63) ----
    {
        ushort_t* orow = h2 + (size_t)bn * ROWLEN + (size_t)l0 * 128;
#pragma unroll
        for (int i = 0; i < 4; ++i) {
            int q = tid + 256 * i;
            int row = q >> 4, c8 = (q & 15) * 8;
            *(short8*)&orow[row * 128 + c8] = *(const short8*)&h1s[row * 136 + c8];
        }
    }
    // ---- z: 4 segment means; thread = (sl, d-pair), b32 reads ----
    {
        int sl = tid >> 6;
        int dp = (tid & 63) * 2;
        float a0 = 0.0f, a1 = 0.0f;
#pragma unroll
        for (int c = 0; c < SCL; ++c) {
            unsigned int u = *reinterpret_cast<const unsigned int*>(
                &h1s[(sl * 16 + c) * 136 + dp]);
            a0 += blo(u);
            a1 += bhi(u);
        }
        zbuf[sl * 136 + dp] = a0 * 0.0625f;
        zbuf[sl * 136 + dp + 1] = a1 * 0.0625f;
    }
    __syncthreads();
    // ---- e1/e2: 64 outputs x 4-way part-interleaved d + shfl reduce ----
    {
        int outi = tid >> 2;         // (sl, which, r)
        int part = tid & 3;          // d residue mod 4
        int sl = outi >> 4;
        int which = (outi >> 3) & 1;
        int r = outi & 7;
        const float* w = which ? gw2 : gw1;
        float a = 0.0f;
#pragma unroll 8
        for (int i = 0; i < 32; ++i) {
            int d = i * 4 + part;    // bank-conflict-free: 16 addrs, 16 banks
            a += zbuf[sl * 136 + d] * w[d * RNK + r];
        }
        a += __shfl_xor(a, 1, 64);
        a += __shfl_xor(a, 2, 64);
        if (part == 0) {
            a += (which ? gb2 : gb1)[r];
            int s = chunk * 4 + sl;
            (which ? e2 : e1)[(((size_t)b * SEG + s) * NVAR + n) * RNK + r] = a;
        }
    }
}

// ---------------- G GEMM: bn-split x2, B frags direct, As dbuf 1-barrier ----
// Launched twice (kh=0 first=1 store; kh=1 first=0 read-add). grid (32, 32):
// blockIdx.x = s (same-s blocks equal mod 8 -> XCD locality for HWf slice),
// blockIdx.y = bnt (32-row m-slab; b = bnt>>1, m-half = bnt&1).
__global__ __launch_bounds__(256) void g_gemm(
    const ushort_t* __restrict__ h2, const ushort_t* __restrict__ HWf,
    float* __restrict__ G, int kh, int first) {
    __shared__ __align__(16) ushort_t As[2][32 * 72];  // 9,216 B
    int s = blockIdx.x;
    int bnt = blockIdx.y;
    int bn0 = bnt * 32;
    int kbase = kh * 1024;
    int tid = threadIdx.x;
    int lane = tid & 63, wv = tid >> 6;
    int quad = lane >> 4, col = lane & 15;
    int mh = wv & 1;   // m half (16 within the 32-slab)
    int ph = wv >> 1;  // p half (48)
    int p0 = ph * 48 + col;

    int arow = tid >> 3;         // 0..31
    int akq = (tid & 7) * 8;     // ushort offset within BK=64 row
    const ushort_t* aptr =
        h2 + (size_t)(bn0 + arow) * ROWLEN + (size_t)s * 2048 + kbase + akq;
    // B frag(kt,kk,i) at hb + kt*6144 + kk*3072 + i*512
    const ushort_t* hb =
        HWf + (size_t)s * 98304 + (size_t)p0 * 32 + quad * 8;

    f32x4 acc[3];  // [p-tile]
#pragma unroll
    for (int i = 0; i < 3; ++i) acc[i] = (f32x4){0.f, 0.f, 0.f, 0.f};

    // ---- prologue: stage As[0], load B frags for kt=0 ----
    short8 pa = *(const short8*)aptr;
    short8 pf[2][2][3];  // [kt parity][kk][i]
#pragma unroll
    for (int kk = 0; kk < 2; ++kk)
#pragma unroll
        for (int i = 0; i < 3; ++i)
            pf[0][kk][i] = *(const short8*)(hb + kk * 3072 + i * 512);
    *(short8*)&As[0][arow * 72 + akq] = pa;
    __syncthreads();

#pragma unroll
    for (int kt = 0; kt < 16; ++kt) {
        const int par = kt & 1;
        if (kt < 15) {
            pa = *(const short8*)(aptr + (kt + 1) * 64);
            const ushort_t* fb = hb + (size_t)(kt + 1) * 6144;
#pragma unroll
            for (int kk = 0; kk < 2; ++kk)
#pragma unroll
                for (int i = 0; i < 3; ++i)
                    pf[par ^ 1][kk][i] =
                        *(const short8*)(fb + kk * 3072 + i * 512);
        }
#pragma unroll
        for (int kk = 0; kk < 2; ++kk) {
            int kc = kk * 32 + quad * 8;
            short8 bnfr =
                *(const short8*)&As[par][(mh * 16 + col) * 72 + kc];
#pragma unroll
            for (int i = 0; i < 3; ++i)
                acc[i] = __builtin_amdgcn_mfma_f32_16x16x32_bf16(
                    pf[par][kk][i], bnfr, acc[i], 0, 0, 0);
        }
        if (kt < 15)
            *(short8*)&As[par ^ 1][arow * 72 + akq] = pa;
        __syncthreads();
    }

    // ---- G write: launch 0 stores, launch 1 read-adds (no atomics) ----
    int b = bnt >> 1;
    int mg = (bnt & 1) * 32 + mh * 16 + col;
#pragma unroll
    for (int i = 0; i < 3; ++i)
#pragma unroll
        for (int r = 0; r < 4; ++r) {
            int p = ph * 48 + i * 16 + quad * 4 + r;
            size_t o = (((size_t)s * BATCH + b) * PRED + p) * NVAR + mg;
            if (first) G[o] = acc[i][r];
            else G[o] += acc[i][r];
        }
}

// ---------------- out mix: softmax + graph mixing, atomicAdd into out -------
__global__ __launch_bounds__(256) void out_mix(
    const float* __restrict__ e1, const float* __restrict__ e2,
    const float* __restrict__ G, float* __restrict__ out,
    float* __restrict__ regacc) {
    __shared__ float adjn[2][32][65];
    __shared__ float Gs[96][65];
    __shared__ float e2s[3][64][8];
    __shared__ float e1s[3][32][8];
    __shared__ float wsum[4];
    int b = blockIdx.x, sg = blockIdx.y, nh = blockIdx.z;
    int s0 = sg * 2;
    int wv = threadIdx.x >> 6, lane = threadIdx.x & 63;

    // stage e1/e2 slices for s = s0-1, s0, s0+1 (zero-fill s<0)
    for (int idx = threadIdx.x; idx < 3 * 64 * 8; idx += 256) {
        int j = idx >> 9, m = (idx >> 3) & 63, r = idx & 7;
        int s = s0 - 1 + j;
        e2s[j][m][r] = (s >= 0)
            ? e2[(((size_t)b * SEG + s) * NVAR + m) * RNK + r] : 0.0f;
    }
    for (int idx = threadIdx.x; idx < 3 * 32 * 8; idx += 256) {
        int j = idx >> 8, nl = (idx >> 3) & 31, r = idx & 7;
        int s = s0 - 1 + j;
        e1s[j][nl][r] = (s >= 0)
            ? e1[(((size_t)b * SEG + s) * NVAR + nh * 32 + nl) * RNK + r] : 0.0f;
    }
    __syncthreads();

    // compute adj rows (lane = m); wave wv handles rows wv*8..wv*8+7
    float regsum = 0.0f;
    for (int t = 0; t < 8; ++t) {
        int nl = wv * 8 + t;
        float a[3];
#pragma unroll
        for (int j = 0; j < 3; ++j) {
            float sc = 0.0f;
#pragma unroll
            for (int r = 0; r < 8; ++r) sc += e1s[j][nl][r] * e2s[j][lane][r];
            sc *= 0.35355339059327373f;  // 1/sqrt(8)
            float mx = sc;
            for (int off = 32; off; off >>= 1)
                mx = fmaxf(mx, __shfl_xor(mx, off, 64));
            float ex = __expf(sc - mx);
            float sm = ex;
            for (int off = 32; off; off >>= 1) sm += __shfl_xor(sm, off, 64);
            a[j] = ex * __builtin_amdgcn_rcpf(sm);
        }
        if (s0 > 0) regsum += fabsf(a[1] - a[0]);  // diff at s0 (vs s0-1)
        regsum += fabsf(a[2] - a[1]);              // diff at s0+1 (vs s0)
        adjn[0][nl][lane] = a[1];
        adjn[1][nl][lane] = a[2];
    }
    __syncthreads();

    int pg = threadIdx.x >> 4;   // p = pg*6 + j
    int ng = threadIdx.x & 15;   // n = nh*32 + ng*2 + i
    float acc[6][2];
#pragma unroll
    for (int j = 0; j < 6; ++j) { acc[j][0] = 0.f; acc[j][1] = 0.f; }

#pragma unroll
    for (int ss = 0; ss < 2; ++ss) {
        int s = s0 + ss;
#pragma unroll
        for (int i = 0; i < 6; ++i) {
            int q = threadIdx.x + 256 * i;
            int row = q >> 4, mq = (q & 15) * 4;
            float4 v = *reinterpret_cast<const float4*>(
                &G[(((size_t)s * BATCH + b) * PRED + row) * NVAR + mq]);
            Gs[row][mq + 0] = v.x; Gs[row][mq + 1] = v.y;
            Gs[row][mq + 2] = v.z; Gs[row][mq + 3] = v.w;
        }
        __syncthreads();
#pragma unroll 4
        for (int m = 0; m < 64; ++m) {
            float a0 = adjn[ss][ng * 2 + 0][m];
            float a1 = adjn[ss][ng * 2 + 1][m];
#pragma unroll
            for (int j = 0; j < 6; ++j) {
                float g = Gs[pg * 6 + j][m];
                acc[j][0] += g * a0;
                acc[j][1] += g * a1;
            }
        }
        __syncthreads();
    }
#pragma unroll
    for (int j = 0; j < 6; ++j)
#pragma unroll
        for (int i = 0; i < 2; ++i) {
            int p = pg * 6 + j, n = nh * 32 + ng * 2 + i;
            atomicAdd(&out[((size_t)b * PRED + p) * NVAR + n], acc[j][i]);
        }
    // block-reduce regsum -> one atomic
    for (int off = 32; off; off >>= 1) regsum += __shfl_xor(regsum, off, 64);
    if (lane == 0) wsum[wv] = regsum;
    __syncthreads();
    if (threadIdx.x == 0)
        atomicAdd(regacc, wsum[0] + wsum[1] + wsum[2] + wsum[3]);
}

// ---------------- fin: write regularizer scalar -----------------------------
__global__ void fin(const float* __restrict__ regacc, float* __restrict__ out,
                    int out_size) {
    out[out_size - 1] = regacc[0] * (1.0f / 65536.0f);
}

extern "C" void kernel_launch(void* const* d_in, const int* in_sizes, int n_in,
                              void* d_out, int out_size, void* d_ws,
                              size_t ws_size, hipStream_t stream) {
    const float* x_enc  = (const float*)d_in[0];
    const float* w_emb  = (const float*)d_in[4];
    const float* b_emb  = (const float*)d_in[5];
    const float* conv_w = (const float*)d_in[6];
    const float* conv_b = (const float*)d_in[7];
    const float* gg_w1  = (const float*)d_in[8];
    const float* gg_b1  = (const float*)d_in[9];
    const float* gg_w2  = (const float*)d_in[10];
    const float* gg_b2  = (const float*)d_in[11];
    const float* head_w = (const float*)d_in[12];
    const float* head_b = (const float*)d_in[13];
    float* out = (float*)d_out;

    // workspace (157,286,404 B): R15 layout. HWf half (6.29 MB) after Bias3;
    // rebuilt per kh half (prep does kh=0, hw_prep does kh=1).
    char* ws = (char*)d_ws;
    ushort_t* h2   = (ushort_t*)(ws);                   // 134,217,728
    float* G       = (float*)(ws + 134217728);          //  12,582,912
    float* e1      = (float*)(ws + 146800640);          //   1,048,576
    float* e2      = (float*)(ws + 147849216);          //   1,048,576
    ushort_t* WTf  = (ushort_t*)(ws + 148897792);       //      98,304
    float* Acoef   = (float*)(ws + 148996096);          //       1,536
    float* Bias3   = (float*)(ws + 148997632);          //       1,536
    ushort_t* HWf  = (ushort_t*)(ws + 149000192);       //   6,291,456 (half)
    float* regacc  = (float*)(ws + 157286400);          //           4

    prep<<<1920, 256, 0, stream>>>(
        conv_w, w_emb, b_emb, conv_b, head_w, head_b,
        WTf, Acoef, Bias3, HWf, out, regacc);
    tcn_mfma<<<dim3(BN, SEQ / 64), 256, 0, stream>>>(
        x_enc, w_emb, b_emb, Acoef, Bias3, WTf, conv_b,
        gg_w1, gg_b1, gg_w2, gg_b2, h2, e1, e2);
    g_gemm<<<dim3(SEG, 32), 256, 0, stream>>>(h2, HWf, G, 0, 1);
    hw_prep<<<1024, 256, 0, stream>>>(head_w, HWf, 1);
    g_gemm<<<dim3(SEG, 32), 256, 0, stream>>>(h2, HWf, G, 1, 0);
    out_mix<<<dim3(BATCH, 16, 2), 256, 0, stream>>>(
        e1, e2, G, out, regacc);
    fin<<<1, 1, 0, stream>>>(regacc, out, out_size);
}

// Round 10
// 292.482 us; speedup vs baseline: 1.2166x; 1.0813x over previous
//
#include <hip/hip_runtime.h>
#include <hip/hip_bf16.h>

// Model_81956565942963: TCN + low-rank dynamic graph + linear head.
// B=16, L=512, N=64, D=128, S=32 x 16, r=8, P=96. f32 in/out.
// R22 = R15 verbatim (session-best 290.4us). Post-mortem of R16-R21: six
// tail restructures (fusion, XCD swizzle, BK=128, reg-dbuf, split-K fuse,
// bn-split) all lost to this configuration; neighborhood sampled densely,
// remaining deltas are at noise level. Locking in the measured best:
//  - rank-1 layer-1 TCN (A[k,co] collapse) + layer-2 MFMA, LDS 21KB
//  - g_gemm: B frags direct from frag-major HWf (L2), As parity dbuf,
//    ONE barrier per k-tile, split-K via two launches (store / read-add)
//  - out_mix: softmax fused, atomicAdd into head_b-pre-initialized out
//  - prep: conv-wt + HWf half 0 + out-init in one launch; hw_prep does kh=1

#define BATCH 16
#define SEQ 512
#define NVAR 64
#define DM 128
#define SEG 32
#define SCL 16
#define RNK 8
#define PRED 96
#define BN (BATCH * NVAR)   // 1024
#define ROWLEN (SEQ * DM)   // 65536

typedef unsigned short ushort_t;
typedef __attribute__((ext_vector_type(8))) short short8;   // 8 bf16
typedef __attribute__((ext_vector_type(4))) float f32x4;

__device__ inline float bf2f(ushort_t u) {
    union { unsigned int i; float f; } x;
    x.i = ((unsigned int)u) << 16;
    return x.f;
}
__device__ inline ushort_t f2bf(float f) {
    union { float f; unsigned int i; } u;
    u.f = f;
    unsigned int x = u.i;
    return (ushort_t)((x + 0x7fffu + ((x >> 16) & 1u)) >> 16);  // RNE
}
__device__ inline unsigned int pkbf(float a, float b) {  // packed bf16 pair
    __hip_bfloat162 h = __float22bfloat162_rn(make_float2(a, b));
    union { __hip_bfloat162 h2; unsigned int u; } c;
    c.h2 = h;
    return c.u;
}
__device__ inline float blo(unsigned int u) {
    union { unsigned int i; float f; } x;
    x.i = u << 16;
    return x.f;
}
__device__ inline float bhi(unsigned int u) {
    union { unsigned int i; float f; } x;
    x.i = u & 0xFFFF0000u;
    return x.f;
}
// gelu(x) = x * sigmoid(2t), t = 0.79788456*x*(1+0.044715*x^2).
// exp(-2t) = 2^(x*(C0 + C1*x^2)), C0 = -2*log2(e)*0.79788456, C1 = C0*0.044715.
__device__ inline float gelu_fast(float x) {
    float x2 = x * x;
    float t2 = x * fmaf(-0.10294854f, x2, -2.3022584f);
    float e;
    asm("v_exp_f32 %0, %1" : "=v"(e) : "v"(t2));
    return x * __builtin_amdgcn_rcpf(1.0f + e);
}

// ---------------- prep: conv-weight prep + head_w half 0 + out init ---------
// blocks 0..511:    wt part (bx = bid>>7, ci = bid&127; 128 threads used)
// blocks 512..1535: hw part kh=0 (k32p = bid-512)
// blocks 1536..1919: out init: out[b][p][n] = head_b[p]
__global__ __launch_bounds__(256) void prep(
    const float* __restrict__ conv_w, const float* __restrict__ w_emb,
    const float* __restrict__ b_emb, const float* __restrict__ conv_b,
    const float* __restrict__ head_w, const float* __restrict__ head_b,
    ushort_t* __restrict__ WTf, float* __restrict__ Acoef,
    float* __restrict__ Bias3, ushort_t* __restrict__ HWf,
    float* __restrict__ out, float* __restrict__ regacc) {
    __shared__ float ts[32 * 97];
    int bid = blockIdx.x;
    if (bid == 0 && threadIdx.x == 0) regacc[0] = 0.f;
    if (bid < 512) {
        int bx = bid >> 7, ci = bid & 127;
        if (threadIdx.x < 128) {
            int co = threadIdx.x;
            if (bx < 3) {
                // layer-2 tap bx -> frag-major bf16
                int kt = ci >> 5, quad = (ci >> 3) & 3, j = ci & 7;
                int ng = co >> 4, col = co & 15;
                int lane = quad * 16 + col;
                WTf[((((size_t)bx * 4 + kt) * 8 + ng) * 64 + lane) * 8 + j] =
                    f2bf(conv_w[(size_t)(3 + bx) * 16384 + (size_t)ci * 128 + co]);
            } else if (ci == 0) {
                // rank-1 collapse of layer 1
                float a0 = 0.f, a1 = 0.f, a2 = 0.f, c0 = 0.f, c1 = 0.f, c2 = 0.f;
                for (int k = 0; k < 128; ++k) {
                    float we = w_emb[k], be = b_emb[k];
                    float w0 = conv_w[((size_t)(0 * 128 + k)) * 128 + co];
                    float w1 = conv_w[((size_t)(1 * 128 + k)) * 128 + co];
                    float w2 = conv_w[((size_t)(2 * 128 + k)) * 128 + co];
                    a0 += we * w0; c0 += be * w0;
                    a1 += we * w1; c1 += be * w1;
                    a2 += we * w2; c2 += be * w2;
                }
                Acoef[0 * 128 + co] = a0;
                Acoef[1 * 128 + co] = a1;
                Acoef[2 * 128 + co] = a2;
                float b0 = conv_b[co];
                Bias3[0 * 128 + co] = b0 + c2;
                Bias3[1 * 128 + co] = b0 + c1 + c2;
                Bias3[2 * 128 + co] = b0 + c0 + c1 + c2;
            }
        }
    } else if (bid < 1536) {
        // head_w f32 [k][p] -> bf16 frag-major, kh = 0
        int k32p = bid - 512;                 // 0..1023
        int s = k32p >> 5, t = k32p & 31;
        int kbase = (s * 64 + t) * 32;        // kh=0
        const float* src = head_w + (size_t)kbase * 96;
        for (int idx = threadIdx.x; idx < 3072; idx += 256) {
            int kk = idx / 96, p = idx - kk * 96;
            ts[kk * 97 + p] = src[idx];
        }
        __syncthreads();
        unsigned int* ob32 =
            reinterpret_cast<unsigned int*>(HWf + (size_t)k32p * 3072);
        for (int odx = threadIdx.x; odx < 1536; odx += 256) {
            int p = odx >> 4, kk = (odx & 15) * 2;
            ob32[odx] = pkbf(ts[kk * 97 + p], ts[(kk + 1) * 97 + p]);
        }
    } else {
        int idx = (bid - 1536) * 256 + threadIdx.x;
        if (idx < BATCH * PRED * NVAR) {
            int p = (idx >> 6) % PRED;
            out[idx] = head_b[p];
        }
    }
}

// ---------------- head_w half-transpose (kh=1 between the two g_gemms) ------
__global__ __launch_bounds__(256) void hw_prep(
    const float* __restrict__ head_w, ushort_t* __restrict__ HWf, int kh) {
    __shared__ float ts[32 * 97];
    int k32p = blockIdx.x;                    // 0..1023
    int s = k32p >> 5, t = k32p & 31;
    int kbase = (s * 64 + kh * 32 + t) * 32;
    const float* src = head_w + (size_t)kbase * 96;
    for (int idx = threadIdx.x; idx < 3072; idx += 256) {
        int kk = idx / 96, p = idx - kk * 96;
        ts[kk * 97 + p] = src[idx];
    }
    __syncthreads();
    unsigned int* ob32 =
        reinterpret_cast<unsigned int*>(HWf + (size_t)k32p * 3072);
    for (int odx = threadIdx.x; odx < 1536; odx += 256) {
        int p = odx >> 4, kk = (odx & 15) * 2;
        ob32[odx] = pkbf(ts[kk * 97 + p], ts[(kk + 1) * 97 + p]);
    }
}

// ---------------- fused TCN (layer1 scalar + layer2 MFMA) + z + e1/e2 ------
__global__ __launch_bounds__(256, 4) void tcn_mfma(
    const float* __restrict__ x, const float* __restrict__ w_emb,
    const float* __restrict__ b_emb, const float* __restrict__ Acoef,
    const float* __restrict__ Bias3, const ushort_t* __restrict__ WTf,
    const float* __restrict__ conv_b,
    const float* __restrict__ gw1, const float* __restrict__ gb1,
    const float* __restrict__ gw2, const float* __restrict__ gb2,
    ushort_t* __restrict__ h2, float* __restrict__ e1, float* __restrict__ e2) {
    __shared__ __align__(16) ushort_t h1s[68 * 136];  // h1, row = li+4; later
                                                      // rows 0..63 = staged h2
    __shared__ float xs[70];                          // x[l0-6 .. l0+63]
    __shared__ float zbuf[4 * 136];                   // segment means (pad 136)

    int bn = blockIdx.x;
    int b = bn >> 6, n = bn & 63;
    int chunk = blockIdx.y;
    int l0 = chunk * 64;
    int tid = threadIdx.x;

    // ---- stage x halo (broadcast scalars) ----
    {
        const float* xb = x + (size_t)b * SEQ * NVAR + n;
        if (tid < 70) {
            int l = l0 - 6 + tid;
            xs[tid] = (l >= 0) ? xb[(size_t)l * NVAR] : 0.0f;
        }
    }
    __syncthreads();

    // ---- layer 1 direct: h1[row][d] = gelu(sum_k x*A) + (x*we+be) ----
    {
        int dp = (tid & 63) * 2;
        float2 A0 = *reinterpret_cast<const float2*>(&Acoef[0 * 128 + dp]);
        float2 A1 = *reinterpret_cast<const float2*>(&Acoef[1 * 128 + dp]);
        float2 A2 = *reinterpret_cast<const float2*>(&Acoef[2 * 128 + dp]);
        float2 BF = *reinterpret_cast<const float2*>(&Bias3[2 * 128 + dp]);
        float2 we2 = *reinterpret_cast<const float2*>(&w_emb[dp]);
        float2 be2 = *reinterpret_cast<const float2*>(&b_emb[dp]);
#pragma unroll
        for (int i = 0; i < 17; ++i) {  // 68 rows x 64 pairs = 17*256
            int row = (tid >> 6) + 4 * i;   // wave-uniform
            int l = l0 - 4 + row;
            unsigned int pk = 0;
            if (l >= 0) {
                float x0 = xs[row], x1 = xs[row + 1], x2 = xs[row + 2];
                float2 bias = BF;
                if (l < 2)  // chunk 0, rows 4/5 only (wave-uniform)
                    bias = *reinterpret_cast<const float2*>(&Bias3[l * 128 + dp]);
                float y0 = fmaf(x0, A0.x, fmaf(x1, A1.x, fmaf(x2, A2.x, bias.x)));
                float y1 = fmaf(x0, A0.y, fmaf(x1, A1.y, fmaf(x2, A2.y, bias.y)));
                float r0 = gelu_fast(y0) + fmaf(x2, we2.x, be2.x);
                float r1 = gelu_fast(y1) + fmaf(x2, we2.y, be2.y);
                pk = pkbf(r0, r1);
            }
            *reinterpret_cast<unsigned int*>(&h1s[row * 136 + dp]) = pk;
        }
    }
    __syncthreads();

    int lane = tid & 63;
    int wv = tid >> 6;
    int quad = lane >> 4;
    int col = lane & 15;
    int cobase = wv * 32;

    // ---- layer 2 MFMA: li = mt*16+col; tap t reads h1s row li+2t ----
    f32x4 acc2[4][2];
#pragma unroll
    for (int mt = 0; mt < 4; ++mt)
#pragma unroll
        for (int nt = 0; nt < 2; ++nt)
            acc2[mt][nt] = (f32x4){0.f, 0.f, 0.f, 0.f};

#pragma unroll
    for (int tap = 0; tap < 3; ++tap) {
        short8 wf0[4], wf1[4];
#pragma unroll
        for (int kt = 0; kt < 4; ++kt) {
            const ushort_t* bp =
                WTf + ((((size_t)tap * 4 + kt) * 8 + wv * 2) * 64 + lane) * 8;
            wf0[kt] = *(const short8*)bp;
            wf1[kt] = *(const short8*)(bp + 512);
        }
#pragma unroll
        for (int kt = 0; kt < 4; ++kt) {
            int kc = kt * 32 + quad * 8;
#pragma unroll
            for (int mt = 0; mt < 4; ++mt) {
                short8 hf = *(const short8*)&h1s[(mt * 16 + col + 2 * tap) * 136 + kc];
                acc2[mt][0] = __builtin_amdgcn_mfma_f32_16x16x32_bf16(wf0[kt], hf, acc2[mt][0], 0, 0, 0);
                acc2[mt][1] = __builtin_amdgcn_mfma_f32_16x16x32_bf16(wf1[kt], hf, acc2[mt][1], 0, 0, 0);
            }
        }
    }

    // ---- epilogue 2: residuals -> regs, barrier, then stage h2 into h1s ----
    {
        uint2 res[4][2];
#pragma unroll
        for (int mt = 0; mt < 4; ++mt) {
            int li = mt * 16 + col;
#pragma unroll
            for (int nt = 0; nt < 2; ++nt) {
                int co = cobase + nt * 16 + quad * 4;
                res[mt][nt] = *reinterpret_cast<const uint2*>(
                    &h1s[(li + 4) * 136 + co]);
            }
        }
        __syncthreads();  // all h1 reads done; h1s rows 0..63 become h2 stage
        float4 bias[2];
        bias[0] = *reinterpret_cast<const float4*>(&conv_b[DM + cobase + quad * 4]);
        bias[1] = *reinterpret_cast<const float4*>(&conv_b[DM + cobase + 16 + quad * 4]);
#pragma unroll
        for (int mt = 0; mt < 4; ++mt) {
            int li = mt * 16 + col;
#pragma unroll
            for (int nt = 0; nt < 2; ++nt) {
                int co = cobase + nt * 16 + quad * 4;
                float h0 = gelu_fast(acc2[mt][nt][0] + bias[nt].x) + blo(res[mt][nt].x);
                float h1 = gelu_fast(acc2[mt][nt][1] + bias[nt].y) + bhi(res[mt][nt].x);
                float h2v = gelu_fast(acc2[mt][nt][2] + bias[nt].z) + blo(res[mt][nt].y);
                float h3 = gelu_fast(acc2[mt][nt][3] + bias[nt].w) + bhi(res[mt][nt].y);
                uint2 pk;
                pk.x = pkbf(h0, h1);
                pk.y = pkbf(h2v, h3);
                *reinterpret_cast<uint2*>(&h1s[li * 136 + co]) = pk;
            }
        }
    }
    __syncthreads();

    // ---- coalesced h2 store (from h1s rows 0..63) ----
    {
        ushort_t* orow = h2 + (size_t)bn * ROWLEN + (size_t)l0 * 128;
#pragma unroll
        for (int i = 0; i < 4; ++i) {
            int q = tid + 256 * i;
            int row = q >> 4, c8 = (q & 15) * 8;
            *(short8*)&orow[row * 128 + c8] = *(const short8*)&h1s[row * 136 + c8];
        }
    }
    // ---- z: 4 segment means; thread = (sl, d-pair), b32 reads ----
    {
        int sl = tid >> 6;
        int dp = (tid & 63) * 2;
        float a0 = 0.0f, a1 = 0.0f;
#pragma unroll
        for (int c = 0; c < SCL; ++c) {
            unsigned int u = *reinterpret_cast<const unsigned int*>(
                &h1s[(sl * 16 + c) * 136 + dp]);
            a0 += blo(u);
            a1 += bhi(u);
        }
        zbuf[sl * 136 + dp] = a0 * 0.0625f;
        zbuf[sl * 136 + dp + 1] = a1 * 0.0625f;
    }
    __syncthreads();
    // ---- e1/e2: 64 outputs x 4-way part-interleaved d + shfl reduce ----
    {
        int outi = tid >> 2;         // (sl, which, r)
        int part = tid & 3;          // d residue mod 4
        int sl = outi >> 4;
        int which = (outi >> 3) & 1;
        int r = outi & 7;
        const float* w = which ? gw2 : gw1;
        float a = 0.0f;
#pragma unroll 8
        for (int i = 0; i < 32; ++i) {
            int d = i * 4 + part;    // bank-conflict-free: 16 addrs, 16 banks
            a += zbuf[sl * 136 + d] * w[d * RNK + r];
        }
        a += __shfl_xor(a, 1, 64);
        a += __shfl_xor(a, 2, 64);
        if (part == 0) {
            a += (which ? gb2 : gb1)[r];
            int s = chunk * 4 + sl;
            (which ? e2 : e1)[(((size_t)b * SEG + s) * NVAR + n) * RNK + r] = a;
        }
    }
}

// ---------------- G GEMM (MFMA): B frags direct from HWf, As dbuf -----------
// Launched twice (kh=0 first=1 store; kh=1 first=0 read-add). grid (32,16).
__global__ __launch_bounds__(256) void g_gemm(
    const ushort_t* __restrict__ h2, const ushort_t* __restrict__ HWf,
    float* __restrict__ G, int kh, int first) {
    __shared__ __align__(16) ushort_t As[2][64 * 72];  // [buf][bn][k]
    int s = blockIdx.x;
    int bnt = blockIdx.y;
    int bn0 = bnt * 64;
    int kbase = kh * 1024;
    int lane = threadIdx.x & 63, wv = threadIdx.x >> 6;
    int quad = lane >> 4, col = lane & 15;
    int mh = wv & 1;   // bn half (32)
    int ph = wv >> 1;  // p half (48)
    int p0 = ph * 48 + col;

    int arow = threadIdx.x >> 2, akq = (threadIdx.x & 3) * 16;
    const ushort_t* aptr =
        h2 + (size_t)(bn0 + arow) * ROWLEN + (size_t)s * 2048 + kbase + akq;
    // B fragment base: frag(kt,kk,i) at hb + kt*6144 + kk*3072 + i*512
    const ushort_t* hb =
        HWf + (size_t)s * 98304 + (size_t)p0 * 32 + quad * 8;

    f32x4 acc[3][2];  // [p-tile][bn-tile]
#pragma unroll
    for (int i = 0; i < 3; ++i)
#pragma unroll
        for (int j = 0; j < 2; ++j) acc[i][j] = (f32x4){0.f, 0.f, 0.f, 0.f};

    // ---- prologue: stage As[0], load B frags for kt=0 ----
    short8 pa0 = *(const short8*)aptr;
    short8 pa1 = *(const short8*)(aptr + 8);
    short8 pf[2][2][3];  // [kt parity][kk][i]
#pragma unroll
    for (int kk = 0; kk < 2; ++kk)
#pragma unroll
        for (int i = 0; i < 3; ++i)
            pf[0][kk][i] = *(const short8*)(hb + kk * 3072 + i * 512);
    *(short8*)&As[0][arow * 72 + akq] = pa0;
    *(short8*)&As[0][arow * 72 + akq + 8] = pa1;
    __syncthreads();

#pragma unroll
    for (int kt = 0; kt < 16; ++kt) {
        const int par = kt & 1;
        if (kt < 15) {
            const ushort_t* ap = aptr + (kt + 1) * 64;
            pa0 = *(const short8*)ap;
            pa1 = *(const short8*)(ap + 8);
            const ushort_t* fb = hb + (size_t)(kt + 1) * 6144;
#pragma unroll
            for (int kk = 0; kk < 2; ++kk)
#pragma unroll
                for (int i = 0; i < 3; ++i)
                    pf[par ^ 1][kk][i] =
                        *(const short8*)(fb + kk * 3072 + i * 512);
        }
#pragma unroll
        for (int kk = 0; kk < 2; ++kk) {
            int kc = kk * 32 + quad * 8;
#pragma unroll
            for (int j = 0; j < 2; ++j) {
                short8 bnfr =
                    *(const short8*)&As[par][(mh * 32 + j * 16 + col) * 72 + kc];
#pragma unroll
                for (int i = 0; i < 3; ++i)
                    acc[i][j] = __builtin_amdgcn_mfma_f32_16x16x32_bf16(
                        pf[par][kk][i], bnfr, acc[i][j], 0, 0, 0);
            }
        }
        if (kt < 15) {
            *(short8*)&As[par ^ 1][arow * 72 + akq] = pa0;
            *(short8*)&As[par ^ 1][arow * 72 + akq + 8] = pa1;
        }
        __syncthreads();
    }

    // ---- G write: launch 0 stores, launch 1 read-adds (no atomics) ----
#pragma unroll
    for (int i = 0; i < 3; ++i)
#pragma unroll
        for (int j = 0; j < 2; ++j)
#pragma unroll
            for (int r = 0; r < 4; ++r) {
                int p = ph * 48 + i * 16 + quad * 4 + r;
                int m = mh * 32 + j * 16 + col;
                size_t o = (((size_t)s * BATCH + bnt) * PRED + p) * NVAR + m;
                if (first) G[o] = acc[i][j][r];
                else G[o] += acc[i][j][r];
            }
}

// ---------------- out mix: softmax + graph mixing, atomicAdd into out -------
__global__ __launch_bounds__(256) void out_mix(
    const float* __restrict__ e1, const float* __restrict__ e2,
    const float* __restrict__ G, float* __restrict__ out,
    float* __restrict__ regacc) {
    __shared__ float adjn[2][32][65];
    __shared__ float Gs[96][65];
    __shared__ float e2s[3][64][8];
    __shared__ float e1s[3][32][8];
    __shared__ float wsum[4];
    int b = blockIdx.x, sg = blockIdx.y, nh = blockIdx.z;
    int s0 = sg * 2;
    int wv = threadIdx.x >> 6, lane = threadIdx.x & 63;

    // stage e1/e2 slices for s = s0-1, s0, s0+1 (zero-fill s<0)
    for (int idx = threadIdx.x; idx < 3 * 64 * 8; idx += 256) {
        int j = idx >> 9, m = (idx >> 3) & 63, r = idx & 7;
        int s = s0 - 1 + j;
        e2s[j][m][r] = (s >= 0)
            ? e2[(((size_t)b * SEG + s) * NVAR + m) * RNK + r] : 0.0f;
    }
    for (int idx = threadIdx.x; idx < 3 * 32 * 8; idx += 256) {
        int j = idx >> 8, nl = (idx >> 3) & 31, r = idx & 7;
        int s = s0 - 1 + j;
        e1s[j][nl][r] = (s >= 0)
            ? e1[(((size_t)b * SEG + s) * NVAR + nh * 32 + nl) * RNK + r] : 0.0f;
    }
    __syncthreads();

    // compute adj rows (lane = m); wave wv handles rows wv*8..wv*8+7
    float regsum = 0.0f;
    for (int t = 0; t < 8; ++t) {
        int nl = wv * 8 + t;
        float a[3];
#pragma unroll
        for (int j = 0; j < 3; ++j) {
            float sc = 0.0f;
#pragma unroll
            for (int r = 0; r < 8; ++r) sc += e1s[j][nl][r] * e2s[j][lane][r];
            sc *= 0.35355339059327373f;  // 1/sqrt(8)
            float mx = sc;
            for (int off = 32; off; off >>= 1)
                mx = fmaxf(mx, __shfl_xor(mx, off, 64));
            float ex = __expf(sc - mx);
            float sm = ex;
            for (int off = 32; off; off >>= 1) sm += __shfl_xor(sm, off, 64);
            a[j] = ex * __builtin_amdgcn_rcpf(sm);
        }
        if (s0 > 0) regsum += fabsf(a[1] - a[0]);  // diff at s0 (vs s0-1)
        regsum += fabsf(a[2] - a[1]);              // diff at s0+1 (vs s0)
        adjn[0][nl][lane] = a[1];
        adjn[1][nl][lane] = a[2];
    }
    __syncthreads();

    int pg = threadIdx.x >> 4;   // p = pg*6 + j
    int ng = threadIdx.x & 15;   // n = nh*32 + ng*2 + i
    float acc[6][2];
#pragma unroll
    for (int j = 0; j < 6; ++j) { acc[j][0] = 0.f; acc[j][1] = 0.f; }

#pragma unroll
    for (int ss = 0; ss < 2; ++ss) {
        int s = s0 + ss;
#pragma unroll
        for (int i = 0; i < 6; ++i) {
            int q = threadIdx.x + 256 * i;
            int row = q >> 4, mq = (q & 15) * 4;
            float4 v = *reinterpret_cast<const float4*>(
                &G[(((size_t)s * BATCH + b) * PRED + row) * NVAR + mq]);
            Gs[row][mq + 0] = v.x; Gs[row][mq + 1] = v.y;
            Gs[row][mq + 2] = v.z; Gs[row][mq + 3] = v.w;
        }
        __syncthreads();
#pragma unroll 4
        for (int m = 0; m < 64; ++m) {
            float a0 = adjn[ss][ng * 2 + 0][m];
            float a1 = adjn[ss][ng * 2 + 1][m];
#pragma unroll
            for (int j = 0; j < 6; ++j) {
                float g = Gs[pg * 6 + j][m];
                acc[j][0] += g * a0;
                acc[j][1] += g * a1;
            }
        }
        __syncthreads();
    }
#pragma unroll
    for (int j = 0; j < 6; ++j)
#pragma unroll
        for (int i = 0; i < 2; ++i) {
            int p = pg * 6 + j, n = nh * 32 + ng * 2 + i;
            atomicAdd(&out[((size_t)b * PRED + p) * NVAR + n], acc[j][i]);
        }
    // block-reduce regsum -> one atomic
    for (int off = 32; off; off >>= 1) regsum += __shfl_xor(regsum, off, 64);
    if (lane == 0) wsum[wv] = regsum;
    __syncthreads();
    if (threadIdx.x == 0)
        atomicAdd(regacc, wsum[0] + wsum[1] + wsum[2] + wsum[3]);
}

// ---------------- fin: write regularizer scalar -----------------------------
__global__ void fin(const float* __restrict__ regacc, float* __restrict__ out,
                    int out_size) {
    out[out_size - 1] = regacc[0] * (1.0f / 65536.0f);
}

extern "C" void kernel_launch(void* const* d_in, const int* in_sizes, int n_in,
                              void* d_out, int out_size, void* d_ws,
                              size_t ws_size, hipStream_t stream) {
    const float* x_enc  = (const float*)d_in[0];
    const float* w_emb  = (const float*)d_in[4];
    const float* b_emb  = (const float*)d_in[5];
    const float* conv_w = (const float*)d_in[6];
    const float* conv_b = (const float*)d_in[7];
    const float* gg_w1  = (const float*)d_in[8];
    const float* gg_b1  = (const float*)d_in[9];
    const float* gg_w2  = (const float*)d_in[10];
    const float* gg_b2  = (const float*)d_in[11];
    const float* head_w = (const float*)d_in[12];
    const float* head_b = (const float*)d_in[13];
    float* out = (float*)d_out;

    // workspace (157,286,404 B): HWf half (6.29 MB) in the gap after Bias3;
    // rebuilt per kh half (prep does kh=0, hw_prep does kh=1).
    char* ws = (char*)d_ws;
    ushort_t* h2   = (ushort_t*)(ws);                   // 134,217,728
    float* G       = (float*)(ws + 134217728);          //  12,582,912
    float* e1      = (float*)(ws + 146800640);          //   1,048,576
    float* e2      = (float*)(ws + 147849216);          //   1,048,576
    ushort_t* WTf  = (ushort_t*)(ws + 148897792);       //      98,304
    float* Acoef   = (float*)(ws + 148996096);          //       1,536
    float* Bias3   = (float*)(ws + 148997632);          //       1,536
    ushort_t* HWf  = (ushort_t*)(ws + 149000192);       //   6,291,456 (half)
    float* regacc  = (float*)(ws + 157286400);          //           4

    prep<<<1920, 256, 0, stream>>>(
        conv_w, w_emb, b_emb, conv_b, head_w, head_b,
        WTf, Acoef, Bias3, HWf, out, regacc);
    tcn_mfma<<<dim3(BN, SEQ / 64), 256, 0, stream>>>(
        x_enc, w_emb, b_emb, Acoef, Bias3, WTf, conv_b,
        gg_w1, gg_b1, gg_w2, gg_b2, h2, e1, e2);
    g_gemm<<<dim3(SEG, BATCH), 256, 0, stream>>>(h2, HWf, G, 0, 1);
    hw_prep<<<1024, 256, 0, stream>>>(head_w, HWf, 1);
    g_gemm<<<dim3(SEG, BATCH), 256, 0, stream>>>(h2, HWf, G, 1, 0);
    out_mix<<<dim3(BATCH, 16, 2), 256, 0, stream>>>(
        e1, e2, G, out, regacc);
    fin<<<1, 1, 0, stream>>>(regacc, out, out_size);
}